// Round 8
// baseline (219.753 us; speedup 1.0000x reference)
//
#include <hip/hip_runtime.h>

#define NN 50000
#define NE 800000
#define NF 64
#define NG 64
#define NC 16
#define NSLICE 16
#define NBKT 196   // buckets of 256 nodes: ceil(NN/256)
#define CH 4096    // edges per scatter block
#define SCAP 6144  // per-bucket LDS stage capacity (mean 4096, sigma~64)

// ---- CSR build: two-level bucket counting sort ---------------------------

__global__ void zero_kernel(int* __restrict__ p, int n) {
    for (int i = threadIdx.x; i < n; i += 256) p[i] = 0;
}

// P1a: per-bucket histogram (LDS-staged)
__global__ void bhist_kernel(const int* __restrict__ dst, int* __restrict__ bhist, int E) {
    __shared__ int lh[NBKT];
    for (int i = threadIdx.x; i < NBKT; i += 256) lh[i] = 0;
    __syncthreads();
    int e = (blockIdx.x * 256 + threadIdx.x) * 4;
    if (e + 3 < E) {
        int4 d = *(const int4*)&dst[e];
        atomicAdd(&lh[d.x >> 8], 1); atomicAdd(&lh[d.y >> 8], 1);
        atomicAdd(&lh[d.z >> 8], 1); atomicAdd(&lh[d.w >> 8], 1);
    } else {
        for (int k = e; k < E; ++k) atomicAdd(&lh[dst[k] >> 8], 1);
    }
    __syncthreads();
    for (int i = threadIdx.x; i < NBKT; i += 256) if (lh[i]) atomicAdd(&bhist[i], lh[i]);
}

// P1b: scan bucket hist -> bucket_base (+total), init bucket cursors
__global__ void bscan_kernel(const int* __restrict__ bhist, int* __restrict__ bbase,
                             int* __restrict__ bcur) {
    int tid = threadIdx.x, lane = tid & 63, wid = tid >> 6;
    int v = (tid < NBKT) ? bhist[tid] : 0;
    int s = v;
    #pragma unroll
    for (int d = 1; d < 64; d <<= 1) { int t = __shfl_up(s, d, 64); if (lane >= d) s += t; }
    __shared__ int ws[4];
    if (lane == 63) ws[wid] = s;
    __syncthreads();
    int woff = 0;
    for (int k = 0; k < wid; ++k) woff += ws[k];
    int excl = woff + s - v;
    if (tid < NBKT) { bbase[tid] = excl; bcur[tid] = excl; }
    if (tid == NBKT) bbase[NBKT] = excl;
}

// P1c: scatter edges into bucket regions of `pairs`, LDS-staged so global
// writes are contiguous bursts per bucket.
__global__ void __launch_bounds__(256) bscatter_kernel(
        const int* __restrict__ src, const int* __restrict__ dst,
        int* __restrict__ bcur, int2* __restrict__ pairs, int E) {
    __shared__ int lhist[NBKT];
    __shared__ int lbase[NBKT];
    __shared__ int gbase[NBKT];
    __shared__ int2 stage[CH];
    __shared__ short bktOf[CH];
    __shared__ int ws[4];
    int tid = threadIdx.x, lane = tid & 63, wid = tid >> 6;
    for (int i = tid; i < NBKT; i += 256) lhist[i] = 0;
    __syncthreads();
    int e0 = blockIdx.x * CH;
    int m = E - e0; if (m > CH) m = CH;
    int es[16], ed[16], er[16];
    #pragma unroll
    for (int k = 0; k < 16; ++k) {
        int i = tid + k * 256;
        if (i < m) {
            es[k] = src[e0 + i];
            ed[k] = dst[e0 + i];
            er[k] = atomicAdd(&lhist[ed[k] >> 8], 1);
        }
    }
    __syncthreads();
    {
        int v = (tid < NBKT) ? lhist[tid] : 0;
        int s = v;
        #pragma unroll
        for (int d = 1; d < 64; d <<= 1) { int t = __shfl_up(s, d, 64); if (lane >= d) s += t; }
        if (lane == 63) ws[wid] = s;
        __syncthreads();
        int woff = 0;
        for (int k = 0; k < wid; ++k) woff += ws[k];
        if (tid < NBKT) {
            lbase[tid] = woff + s - v;
            gbase[tid] = v ? atomicAdd(&bcur[tid], v) : 0;
        }
    }
    __syncthreads();
    #pragma unroll
    for (int k = 0; k < 16; ++k) {
        int i = tid + k * 256;
        if (i < m) {
            int b = ed[k] >> 8;
            int pos = lbase[b] + er[k];
            stage[pos] = make_int2(es[k], ed[k]);
            bktOf[pos] = (short)b;
        }
    }
    __syncthreads();
    for (int i = tid; i < m; i += 256) {
        int b = bktOf[i];
        pairs[gbase[b] + (i - lbase[b])] = stage[i];
    }
}

// P2: per-bucket counting sort by dst -> csr_src (coalesced), row_ptr, dinv,
// fused prescale Xs = x * dinv for this bucket's node range.
__global__ void __launch_bounds__(256) bsort_kernel(
        const int2* __restrict__ pairs, const int* __restrict__ bbase,
        int* __restrict__ csr_src, int* __restrict__ row_ptr, float* __restrict__ dinv,
        const float* __restrict__ x, float* __restrict__ Xs, int n) {
    __shared__ int lh[256];
    __shared__ int lcur[256];
    __shared__ float sdv[256];
    __shared__ int ws[4];
    __shared__ int ssrc[SCAP];
    int tid = threadIdx.x, lane = tid & 63, wid = tid >> 6;
    int b = blockIdx.x;
    int n0 = b << 8;
    int nodes = n - n0; if (nodes > 256) nodes = 256;
    int g0 = bbase[b], cnt = bbase[b + 1] - g0;
    lh[tid] = 0;
    __syncthreads();
    for (int i = tid; i < cnt; i += 256) atomicAdd(&lh[pairs[g0 + i].y - n0], 1);
    __syncthreads();
    int v = lh[tid];
    int s = v;
    #pragma unroll
    for (int d = 1; d < 64; d <<= 1) { int t = __shfl_up(s, d, 64); if (lane >= d) s += t; }
    if (lane == 63) ws[wid] = s;
    __syncthreads();
    int woff = 0;
    for (int k = 0; k < wid; ++k) woff += ws[k];
    int excl = woff + s - v;
    lcur[tid] = excl;
    float dv = rsqrtf((float)v + 1.0f);
    sdv[tid] = dv;
    if (tid < nodes) {
        row_ptr[n0 + tid] = g0 + excl;
        dinv[n0 + tid] = dv;
    }
    if (b == NBKT - 1 && tid == 0) row_ptr[n] = bbase[NBKT];
    __syncthreads();
    if (cnt <= SCAP) {
        for (int i = tid; i < cnt; i += 256) {
            int2 p = pairs[g0 + i];
            int pos = atomicAdd(&lcur[p.y - n0], 1);
            ssrc[pos] = p.x;
        }
        __syncthreads();
        for (int i = tid; i < cnt; i += 256) csr_src[g0 + i] = ssrc[i];
    } else {
        for (int i = tid; i < cnt; i += 256) {
            int2 p = pairs[g0 + i];
            int pos = atomicAdd(&lcur[p.y - n0], 1);
            csr_src[g0 + pos] = p.x;
        }
    }
    const float4* x4 = (const float4*)x;
    float4* Xs4 = (float4*)Xs;
    int t0 = n0 << 4;
    int tcnt = nodes << 4;
    for (int t = tid; t < tcnt; t += 256) {
        float4 vv = x4[t0 + t];
        float d = sdv[t >> 4];
        vv.x *= d; vv.y *= d; vv.z *= d; vv.w *= d;
        Xs4[t0 + t] = vv;
    }
}

// ---- fused GCN layer: W in VGPRs, agg broadcast via LDS -------------------
// 4 waves/block, 8 nodes/wave (block = 32 consecutive nodes).
// Per node: wave gathers neighbor rows (4 grp x 16 lanes x float4),
// xor-reduces, stages agg in sAgg[wave], then all lanes do 64 FMAs against
// their register-resident W column with broadcast (same-address) LDS reads.
__global__ void __launch_bounds__(256) layer_kernel(
        const float* __restrict__ Xs, const int* __restrict__ row_ptr,
        const int* __restrict__ csr_src, const float* __restrict__ dinv,
        const float* __restrict__ W, const float* __restrict__ bias,
        float* __restrict__ out, int n, int do_relu, int scale_out) {
    __shared__ __align__(16) float sAgg[4][64];
    int wv = threadIdx.x >> 6, lane = threadIdx.x & 63;
    int grp = lane >> 4, sub = lane & 15;
    const float4* X4 = (const float4*)Xs;

    // W column `lane` -> 64 VGPRs (each k-load is lane-consecutive, L2-hit)
    float wreg[64];
    #pragma unroll
    for (int k = 0; k < 64; ++k) wreg[k] = W[k * 64 + lane];
    float bj = bias[lane];

    int base = blockIdx.x * 32 + wv * 8;
    for (int nd = 0; nd < 8; ++nd) {
        int node = base + nd;
        float4 acc = make_float4(0.f, 0.f, 0.f, 0.f);
        if (node < n) {
            int s0 = row_ptr[node], s1 = row_ptr[node + 1];
            for (int tb = s0; tb < s1; tb += 64) {
                int m = s1 - tb; if (m > 64) m = 64;
                int ld = (lane < m) ? lane : (m - 1);
                int idx = csr_src[tb + ld];
                for (int e0 = grp; e0 < m; e0 += 16) {
                    int e1 = e0 + 4, e2 = e0 + 8, e3 = e0 + 12;
                    int i0 = __shfl(idx, e0, 64);
                    int i1 = __shfl(idx, (e1 < m) ? e1 : e0, 64);
                    int i2 = __shfl(idx, (e2 < m) ? e2 : e0, 64);
                    int i3 = __shfl(idx, (e3 < m) ? e3 : e0, 64);
                    float w1 = (e1 < m) ? 1.f : 0.f;
                    float w2 = (e2 < m) ? 1.f : 0.f;
                    float w3 = (e3 < m) ? 1.f : 0.f;
                    float4 v0 = X4[(unsigned)(i0 * 16 + sub)];
                    float4 v1 = X4[(unsigned)(i1 * 16 + sub)];
                    float4 v2 = X4[(unsigned)(i2 * 16 + sub)];
                    float4 v3 = X4[(unsigned)(i3 * 16 + sub)];
                    acc.x += v0.x; acc.y += v0.y; acc.z += v0.z; acc.w += v0.w;
                    acc.x = fmaf(w1, v1.x, acc.x); acc.y = fmaf(w1, v1.y, acc.y);
                    acc.z = fmaf(w1, v1.z, acc.z); acc.w = fmaf(w1, v1.w, acc.w);
                    acc.x = fmaf(w2, v2.x, acc.x); acc.y = fmaf(w2, v2.y, acc.y);
                    acc.z = fmaf(w2, v2.z, acc.z); acc.w = fmaf(w2, v2.w, acc.w);
                    acc.x = fmaf(w3, v3.x, acc.x); acc.y = fmaf(w3, v3.y, acc.y);
                    acc.z = fmaf(w3, v3.z, acc.z); acc.w = fmaf(w3, v3.w, acc.w);
                }
            }
            if (grp == 0) {  // self-loop (already dinv-scaled)
                float4 sv = X4[(unsigned)(node * 16 + sub)];
                acc.x += sv.x; acc.y += sv.y; acc.z += sv.z; acc.w += sv.w;
            }
        }
        // reduce the 4 edge-groups; lanes (sub, sub+16, ...) end identical
        acc.x += __shfl_xor(acc.x, 16, 64); acc.y += __shfl_xor(acc.y, 16, 64);
        acc.z += __shfl_xor(acc.z, 16, 64); acc.w += __shfl_xor(acc.w, 16, 64);
        acc.x += __shfl_xor(acc.x, 32, 64); acc.y += __shfl_xor(acc.y, 32, 64);
        acc.z += __shfl_xor(acc.z, 32, 64); acc.w += __shfl_xor(acc.w, 32, 64);

        if (grp == 0) *(float4*)&sAgg[wv][sub * 4] = acc;
        __syncthreads();   // order write -> broadcast reads (uniform trip count)

        // matvec: o = sum_k agg[k] * W[k][lane], broadcast reads (no conflicts)
        float o = 0.f;
        const float4* sa = (const float4*)sAgg[wv];
        #pragma unroll
        for (int c = 0; c < 16; ++c) {
            float4 a = sa[c];
            o = fmaf(a.x, wreg[4 * c + 0], o);
            o = fmaf(a.y, wreg[4 * c + 1], o);
            o = fmaf(a.z, wreg[4 * c + 2], o);
            o = fmaf(a.w, wreg[4 * c + 3], o);
        }
        if (node < n) {
            float di = dinv[node];
            float vv = o * di + bj;
            if (do_relu) vv = fmaxf(vv, 0.f);
            if (scale_out) vv *= di;
            out[(unsigned)(node * 64 + lane)] = vv;
        }
        __syncthreads();   // protect sAgg before next iteration's overwrite
    }
}

// ---- pooling / classifier ------------------------------------------------

__global__ void pool1_kernel(const float* __restrict__ H, const int* __restrict__ batch,
                             float* __restrict__ partial, int n) {
    int g = blockIdx.x >> 4, sl = blockIdx.x & (NSLICE - 1);
    int lo = 0, hi = n;
    while (lo < hi) { int m = (lo + hi) >> 1; if (batch[m] < g) lo = m + 1; else hi = m; }
    int start = lo;
    lo = start; hi = n;
    while (lo < hi) { int m = (lo + hi) >> 1; if (batch[m] < g + 1) lo = m + 1; else hi = m; }
    int end = lo;
    int len = end - start;
    int ss = start + (int)((long long)len * sl / NSLICE);
    int se = start + (int)((long long)len * (sl + 1) / NSLICE);

    int f = threadIdx.x & 63, c = threadIdx.x >> 6;
    float s = 0.f, m = -INFINITY;
    for (int i = ss + c; i < se; i += 4) {
        float v = H[i * NF + f];
        s += v; m = fmaxf(m, v);
    }
    __shared__ float ssh[4][64], smh[4][64];
    ssh[c][f] = s; smh[c][f] = m;
    __syncthreads();
    if (c == 0) {
        float sum = ssh[0][f] + ssh[1][f] + ssh[2][f] + ssh[3][f];
        float mx = fmaxf(fmaxf(smh[0][f], smh[1][f]), fmaxf(smh[2][f], smh[3][f]));
        partial[(size_t)blockIdx.x * 128 + f] = sum;
        partial[(size_t)blockIdx.x * 128 + 64 + f] = mx;
    }
}

__global__ void pool2_kernel(const float* __restrict__ partial, const int* __restrict__ batch,
                             const float* __restrict__ Wlin, const float* __restrict__ blin,
                             float* __restrict__ out, int n) {
    int g = blockIdx.x;
    int t = threadIdx.x;  // 128
    __shared__ float pooled[128];
    if (t < 64) {
        float sum = 0.f;
        for (int sl = 0; sl < NSLICE; ++sl) sum += partial[((size_t)g * NSLICE + sl) * 128 + t];
        int lo = 0, hi = n;
        while (lo < hi) { int m = (lo + hi) >> 1; if (batch[m] < g) lo = m + 1; else hi = m; }
        int start = lo;
        lo = start; hi = n;
        while (lo < hi) { int m = (lo + hi) >> 1; if (batch[m] < g + 1) lo = m + 1; else hi = m; }
        int cnt = lo - start;
        pooled[t] = sum / fmaxf((float)cnt, 1.0f);
    } else {
        int f = t - 64;
        float mx = -INFINITY;
        for (int sl = 0; sl < NSLICE; ++sl)
            mx = fmaxf(mx, partial[((size_t)g * NSLICE + sl) * 128 + 64 + f]);
        pooled[t] = mx;
    }
    __syncthreads();
    if (t < NC) {
        float acc = blin[t];
        #pragma unroll 8
        for (int k = 0; k < 128; ++k) acc = fmaf(pooled[k], Wlin[k * NC + t], acc);
        out[g * NC + t] = acc;
    }
}

// ---- launch ---------------------------------------------------------------

extern "C" void kernel_launch(void* const* d_in, const int* in_sizes, int n_in,
                              void* d_out, int out_size, void* d_ws, size_t ws_size,
                              hipStream_t stream) {
    const float* x     = (const float*)d_in[0];
    const int*   ei    = (const int*)d_in[1];
    const int*   batch = (const int*)d_in[2];
    const float* W1    = (const float*)d_in[3];
    const float* b1    = (const float*)d_in[4];
    const float* W2    = (const float*)d_in[5];
    const float* b2    = (const float*)d_in[6];
    const float* W3    = (const float*)d_in[7];
    const float* b3    = (const float*)d_in[8];
    const float* Wlin  = (const float*)d_in[9];
    const float* blin  = (const float*)d_in[10];
    const int* src = ei;
    const int* dst = ei + NE;
    float* out = (float*)d_out;

    // workspace layout (all offsets keep 16B alignment)
    int*   bhist   = (int*)d_ws;                    // 256
    int*   bbase   = bhist + 256;                   // 256 (uses NBKT+1)
    int*   bcur    = bbase + 256;                   // 256
    int*   row_ptr = bcur + 256;                    // 50008
    int*   csr_src = row_ptr + 50008;               // 800000
    float* dinv    = (float*)(csr_src + NE);        // 50008
    float* bufA    = dinv + 50008;                  // 3.2M
    float* bufB    = bufA + (size_t)NN * NF;        // 3.2M (aliased as pairs in build)
    float* partial = bufB + (size_t)NN * NF;        // 131072
    int2*  pairs   = (int2*)bufB;                   // 6.4MB <= bufB, used only pre-layer

    // CSR build (bucket counting sort) + dinv + prescale
    zero_kernel<<<1, 256, 0, stream>>>(bhist, 256);
    bhist_kernel<<<(NE / 4 + 255) / 256, 256, 0, stream>>>(dst, bhist, NE);
    bscan_kernel<<<1, 256, 0, stream>>>(bhist, bbase, bcur);
    bscatter_kernel<<<(NE + CH - 1) / CH, 256, 0, stream>>>(src, dst, bcur, pairs, NE);
    bsort_kernel<<<NBKT, 256, 0, stream>>>(pairs, bbase, csr_src, row_ptr, dinv, x, bufA, NN);

    // 3 fused GCN layers (32 nodes per block)
    int lgrid = (NN + 31) / 32;
    layer_kernel<<<lgrid, 256, 0, stream>>>(bufA, row_ptr, csr_src, dinv, W1, b1,
                                            bufB, NN, 1, 1);
    layer_kernel<<<lgrid, 256, 0, stream>>>(bufB, row_ptr, csr_src, dinv, W2, b2,
                                            bufA, NN, 1, 1);
    layer_kernel<<<lgrid, 256, 0, stream>>>(bufA, row_ptr, csr_src, dinv, W3, b3,
                                            bufB, NN, 0, 0);

    // two-stage pool + fused classifier
    pool1_kernel<<<NG * NSLICE, 256, 0, stream>>>(bufB, batch, partial, NN);
    pool2_kernel<<<NG, 128, 0, stream>>>(partial, batch, Wlin, blin, out, NN);
}

// Round 9
// 191.676 us; speedup vs baseline: 1.1465x; 1.1465x over previous
//
#include <hip/hip_runtime.h>

#define NN 50000
#define NE 800000
#define NF 64
#define NG 64
#define NC 16
#define NSLICE 16
#define NBKT 196   // buckets of 256 nodes: ceil(NN/256)
#define CH 4096    // edges per scatter block
#define SCAP 6144  // per-bucket LDS stage capacity (mean 4096, sigma~64)

// ---- CSR build: two-level bucket counting sort ---------------------------

__global__ void zero_kernel(int* __restrict__ p, int n) {
    for (int i = threadIdx.x; i < n; i += 256) p[i] = 0;
}

// P1a: per-bucket histogram (LDS-staged)
__global__ void bhist_kernel(const int* __restrict__ dst, int* __restrict__ bhist, int E) {
    __shared__ int lh[NBKT];
    for (int i = threadIdx.x; i < NBKT; i += 256) lh[i] = 0;
    __syncthreads();
    int e = (blockIdx.x * 256 + threadIdx.x) * 4;
    if (e + 3 < E) {
        int4 d = *(const int4*)&dst[e];
        atomicAdd(&lh[d.x >> 8], 1); atomicAdd(&lh[d.y >> 8], 1);
        atomicAdd(&lh[d.z >> 8], 1); atomicAdd(&lh[d.w >> 8], 1);
    } else {
        for (int k = e; k < E; ++k) atomicAdd(&lh[dst[k] >> 8], 1);
    }
    __syncthreads();
    for (int i = threadIdx.x; i < NBKT; i += 256) if (lh[i]) atomicAdd(&bhist[i], lh[i]);
}

// P1b: scan bucket hist -> bucket_base (+total), init bucket cursors
__global__ void bscan_kernel(const int* __restrict__ bhist, int* __restrict__ bbase,
                             int* __restrict__ bcur) {
    int tid = threadIdx.x, lane = tid & 63, wid = tid >> 6;
    int v = (tid < NBKT) ? bhist[tid] : 0;
    int s = v;
    #pragma unroll
    for (int d = 1; d < 64; d <<= 1) { int t = __shfl_up(s, d, 64); if (lane >= d) s += t; }
    __shared__ int ws[4];
    if (lane == 63) ws[wid] = s;
    __syncthreads();
    int woff = 0;
    for (int k = 0; k < wid; ++k) woff += ws[k];
    int excl = woff + s - v;
    if (tid < NBKT) { bbase[tid] = excl; bcur[tid] = excl; }
    if (tid == NBKT) bbase[NBKT] = excl;
}

// P1c: scatter edges into bucket regions of `pairs`, LDS-staged so global
// writes are contiguous bursts per bucket.
__global__ void __launch_bounds__(256) bscatter_kernel(
        const int* __restrict__ src, const int* __restrict__ dst,
        int* __restrict__ bcur, int2* __restrict__ pairs, int E) {
    __shared__ int lhist[NBKT];
    __shared__ int lbase[NBKT];
    __shared__ int gbase[NBKT];
    __shared__ int2 stage[CH];
    __shared__ short bktOf[CH];
    __shared__ int ws[4];
    int tid = threadIdx.x, lane = tid & 63, wid = tid >> 6;
    for (int i = tid; i < NBKT; i += 256) lhist[i] = 0;
    __syncthreads();
    int e0 = blockIdx.x * CH;
    int m = E - e0; if (m > CH) m = CH;
    int es[16], ed[16], er[16];
    #pragma unroll
    for (int k = 0; k < 16; ++k) {
        int i = tid + k * 256;
        if (i < m) {
            es[k] = src[e0 + i];
            ed[k] = dst[e0 + i];
            er[k] = atomicAdd(&lhist[ed[k] >> 8], 1);
        }
    }
    __syncthreads();
    {
        int v = (tid < NBKT) ? lhist[tid] : 0;
        int s = v;
        #pragma unroll
        for (int d = 1; d < 64; d <<= 1) { int t = __shfl_up(s, d, 64); if (lane >= d) s += t; }
        if (lane == 63) ws[wid] = s;
        __syncthreads();
        int woff = 0;
        for (int k = 0; k < wid; ++k) woff += ws[k];
        if (tid < NBKT) {
            lbase[tid] = woff + s - v;
            gbase[tid] = v ? atomicAdd(&bcur[tid], v) : 0;
        }
    }
    __syncthreads();
    #pragma unroll
    for (int k = 0; k < 16; ++k) {
        int i = tid + k * 256;
        if (i < m) {
            int b = ed[k] >> 8;
            int pos = lbase[b] + er[k];
            stage[pos] = make_int2(es[k], ed[k]);
            bktOf[pos] = (short)b;
        }
    }
    __syncthreads();
    for (int i = tid; i < m; i += 256) {
        int b = bktOf[i];
        pairs[gbase[b] + (i - lbase[b])] = stage[i];
    }
}

// P2: per-bucket counting sort by dst -> csr_src (coalesced), row_ptr, dinv,
// fused prescale Xs = x * dinv for this bucket's node range.
__global__ void __launch_bounds__(256) bsort_kernel(
        const int2* __restrict__ pairs, const int* __restrict__ bbase,
        int* __restrict__ csr_src, int* __restrict__ row_ptr, float* __restrict__ dinv,
        const float* __restrict__ x, float* __restrict__ Xs, int n) {
    __shared__ int lh[256];
    __shared__ int lcur[256];
    __shared__ float sdv[256];
    __shared__ int ws[4];
    __shared__ int ssrc[SCAP];
    int tid = threadIdx.x, lane = tid & 63, wid = tid >> 6;
    int b = blockIdx.x;
    int n0 = b << 8;
    int nodes = n - n0; if (nodes > 256) nodes = 256;
    int g0 = bbase[b], cnt = bbase[b + 1] - g0;
    lh[tid] = 0;
    __syncthreads();
    for (int i = tid; i < cnt; i += 256) atomicAdd(&lh[pairs[g0 + i].y - n0], 1);
    __syncthreads();
    int v = lh[tid];
    int s = v;
    #pragma unroll
    for (int d = 1; d < 64; d <<= 1) { int t = __shfl_up(s, d, 64); if (lane >= d) s += t; }
    if (lane == 63) ws[wid] = s;
    __syncthreads();
    int woff = 0;
    for (int k = 0; k < wid; ++k) woff += ws[k];
    int excl = woff + s - v;
    lcur[tid] = excl;
    float dv = rsqrtf((float)v + 1.0f);
    sdv[tid] = dv;
    if (tid < nodes) {
        row_ptr[n0 + tid] = g0 + excl;
        dinv[n0 + tid] = dv;
    }
    if (b == NBKT - 1 && tid == 0) row_ptr[n] = bbase[NBKT];
    __syncthreads();
    if (cnt <= SCAP) {
        for (int i = tid; i < cnt; i += 256) {
            int2 p = pairs[g0 + i];
            int pos = atomicAdd(&lcur[p.y - n0], 1);
            ssrc[pos] = p.x;
        }
        __syncthreads();
        for (int i = tid; i < cnt; i += 256) csr_src[g0 + i] = ssrc[i];
    } else {
        for (int i = tid; i < cnt; i += 256) {
            int2 p = pairs[g0 + i];
            int pos = atomicAdd(&lcur[p.y - n0], 1);
            csr_src[g0 + pos] = p.x;
        }
    }
    const float4* x4 = (const float4*)x;
    float4* Xs4 = (float4*)Xs;
    int t0 = n0 << 4;
    int tcnt = nodes << 4;
    for (int t = tid; t < tcnt; t += 256) {
        float4 vv = x4[t0 + t];
        float d = sdv[t >> 4];
        vv.x *= d; vv.y *= d; vv.z *= d; vv.w *= d;
        Xs4[t0 + t] = vv;
    }
}

// ---- fused GCN layer (R6 structure, conflict-free staging, 4 nodes/wave) --
// Per node: wave gathers neighbor rows (4 grp x 16 lanes x float4),
// xor-reduces, then matvec via readlane broadcast against xor-swizzled W^T
// in LDS (reads 2-way = free; staging writes permutation-per-phase = free).
__global__ void __launch_bounds__(256) layer_kernel(
        const float* __restrict__ Xs, const int* __restrict__ row_ptr,
        const int* __restrict__ csr_src, const float* __restrict__ dinv,
        const float* __restrict__ W, const float* __restrict__ bias,
        float* __restrict__ out, int n, int do_relu, int scale_out) {
    __shared__ __align__(16) float sWt[64 * 64];  // row j: 16 xor-swizzled chunks
    {
        int j = threadIdx.x & 63;
        int c0 = (threadIdx.x >> 6) * 4;
        #pragma unroll
        for (int it = 0; it < 4; ++it) {
            int c = c0 + it;
            float4 w;
            w.x = W[(4 * c + 0) * 64 + j];   // coalesced 256B per phase
            w.y = W[(4 * c + 1) * 64 + j];
            w.z = W[(4 * c + 2) * 64 + j];
            w.w = W[(4 * c + 3) * 64 + j];
            *(float4*)&sWt[j * 64 + ((c ^ (j & 15)) * 4)] = w;  // conflict-free
        }
    }
    __syncthreads();

    int wv = threadIdx.x >> 6, lane = threadIdx.x & 63;
    int grp = lane >> 4, sub = lane & 15;
    const float4* X4 = (const float4*)Xs;
    int base = blockIdx.x * 16 + wv * 4;

    for (int nd = 0; nd < 4; ++nd) {
        int node = base + nd;
        if (node >= n) break;   // wave-uniform

        float4 acc = make_float4(0.f, 0.f, 0.f, 0.f);
        int s0 = row_ptr[node], s1 = row_ptr[node + 1];
        for (int tb = s0; tb < s1; tb += 64) {
            int m = s1 - tb; if (m > 64) m = 64;
            int ld = (lane < m) ? lane : (m - 1);
            int idx = csr_src[tb + ld];
            for (int e0 = grp; e0 < m; e0 += 16) {
                int e1 = e0 + 4, e2 = e0 + 8, e3 = e0 + 12;
                int i0 = __shfl(idx, e0, 64);
                int i1 = __shfl(idx, (e1 < m) ? e1 : e0, 64);
                int i2 = __shfl(idx, (e2 < m) ? e2 : e0, 64);
                int i3 = __shfl(idx, (e3 < m) ? e3 : e0, 64);
                float w1 = (e1 < m) ? 1.f : 0.f;
                float w2 = (e2 < m) ? 1.f : 0.f;
                float w3 = (e3 < m) ? 1.f : 0.f;
                float4 v0 = X4[(unsigned)(i0 * 16 + sub)];
                float4 v1 = X4[(unsigned)(i1 * 16 + sub)];
                float4 v2 = X4[(unsigned)(i2 * 16 + sub)];
                float4 v3 = X4[(unsigned)(i3 * 16 + sub)];
                acc.x += v0.x; acc.y += v0.y; acc.z += v0.z; acc.w += v0.w;
                acc.x = fmaf(w1, v1.x, acc.x); acc.y = fmaf(w1, v1.y, acc.y);
                acc.z = fmaf(w1, v1.z, acc.z); acc.w = fmaf(w1, v1.w, acc.w);
                acc.x = fmaf(w2, v2.x, acc.x); acc.y = fmaf(w2, v2.y, acc.y);
                acc.z = fmaf(w2, v2.z, acc.z); acc.w = fmaf(w2, v2.w, acc.w);
                acc.x = fmaf(w3, v3.x, acc.x); acc.y = fmaf(w3, v3.y, acc.y);
                acc.z = fmaf(w3, v3.z, acc.z); acc.w = fmaf(w3, v3.w, acc.w);
            }
        }
        // self-loop (already dinv-scaled)
        if (grp == 0) {
            float4 sv = X4[(unsigned)(node * 16 + sub)];
            acc.x += sv.x; acc.y += sv.y; acc.z += sv.z; acc.w += sv.w;
        }
        // reduce the 4 edge-groups; lane ends with agg[4*sub .. 4*sub+3]
        acc.x += __shfl_xor(acc.x, 16, 64); acc.y += __shfl_xor(acc.y, 16, 64);
        acc.z += __shfl_xor(acc.z, 16, 64); acc.w += __shfl_xor(acc.w, 16, 64);
        acc.x += __shfl_xor(acc.x, 32, 64); acc.y += __shfl_xor(acc.y, 32, 64);
        acc.z += __shfl_xor(acc.z, 32, 64); acc.w += __shfl_xor(acc.w, 32, 64);

        // matvec: out_j = sum_c sum_r agg[4c+r] * W[4c+r][j]
        float o = 0.f;
        #pragma unroll
        for (int c = 0; c < 16; ++c) {
            float4 wvv = *(const float4*)&sWt[lane * 64 + ((c ^ (lane & 15)) * 4)];
            float a0 = __int_as_float(__builtin_amdgcn_readlane(__float_as_int(acc.x), c));
            float a1 = __int_as_float(__builtin_amdgcn_readlane(__float_as_int(acc.y), c));
            float a2 = __int_as_float(__builtin_amdgcn_readlane(__float_as_int(acc.z), c));
            float a3 = __int_as_float(__builtin_amdgcn_readlane(__float_as_int(acc.w), c));
            o = fmaf(a0, wvv.x, o); o = fmaf(a1, wvv.y, o);
            o = fmaf(a2, wvv.z, o); o = fmaf(a3, wvv.w, o);
        }
        float di = dinv[node];
        float vv = o * di + bias[lane];
        if (do_relu) vv = fmaxf(vv, 0.f);
        if (scale_out) vv *= di;
        out[(unsigned)(node * 64 + lane)] = vv;
    }
}

// ---- pooling / classifier ------------------------------------------------

__global__ void pool1_kernel(const float* __restrict__ H, const int* __restrict__ batch,
                             float* __restrict__ partial, int n) {
    int g = blockIdx.x >> 4, sl = blockIdx.x & (NSLICE - 1);
    int lo = 0, hi = n;
    while (lo < hi) { int m = (lo + hi) >> 1; if (batch[m] < g) lo = m + 1; else hi = m; }
    int start = lo;
    lo = start; hi = n;
    while (lo < hi) { int m = (lo + hi) >> 1; if (batch[m] < g + 1) lo = m + 1; else hi = m; }
    int end = lo;
    int len = end - start;
    int ss = start + (int)((long long)len * sl / NSLICE);
    int se = start + (int)((long long)len * (sl + 1) / NSLICE);

    int f = threadIdx.x & 63, c = threadIdx.x >> 6;
    float s = 0.f, m = -INFINITY;
    for (int i = ss + c; i < se; i += 4) {
        float v = H[i * NF + f];
        s += v; m = fmaxf(m, v);
    }
    __shared__ float ssh[4][64], smh[4][64];
    ssh[c][f] = s; smh[c][f] = m;
    __syncthreads();
    if (c == 0) {
        float sum = ssh[0][f] + ssh[1][f] + ssh[2][f] + ssh[3][f];
        float mx = fmaxf(fmaxf(smh[0][f], smh[1][f]), fmaxf(smh[2][f], smh[3][f]));
        partial[(size_t)blockIdx.x * 128 + f] = sum;
        partial[(size_t)blockIdx.x * 128 + 64 + f] = mx;
    }
}

__global__ void pool2_kernel(const float* __restrict__ partial, const int* __restrict__ batch,
                             const float* __restrict__ Wlin, const float* __restrict__ blin,
                             float* __restrict__ out, int n) {
    int g = blockIdx.x;
    int t = threadIdx.x;  // 128
    __shared__ float pooled[128];
    if (t < 64) {
        float sum = 0.f;
        for (int sl = 0; sl < NSLICE; ++sl) sum += partial[((size_t)g * NSLICE + sl) * 128 + t];
        int lo = 0, hi = n;
        while (lo < hi) { int m = (lo + hi) >> 1; if (batch[m] < g) lo = m + 1; else hi = m; }
        int start = lo;
        lo = start; hi = n;
        while (lo < hi) { int m = (lo + hi) >> 1; if (batch[m] < g + 1) lo = m + 1; else hi = m; }
        int cnt = lo - start;
        pooled[t] = sum / fmaxf((float)cnt, 1.0f);
    } else {
        int f = t - 64;
        float mx = -INFINITY;
        for (int sl = 0; sl < NSLICE; ++sl)
            mx = fmaxf(mx, partial[((size_t)g * NSLICE + sl) * 128 + 64 + f]);
        pooled[t] = mx;
    }
    __syncthreads();
    if (t < NC) {
        float acc = blin[t];
        #pragma unroll 8
        for (int k = 0; k < 128; ++k) acc = fmaf(pooled[k], Wlin[k * NC + t], acc);
        out[g * NC + t] = acc;
    }
}

// ---- launch ---------------------------------------------------------------

extern "C" void kernel_launch(void* const* d_in, const int* in_sizes, int n_in,
                              void* d_out, int out_size, void* d_ws, size_t ws_size,
                              hipStream_t stream) {
    const float* x     = (const float*)d_in[0];
    const int*   ei    = (const int*)d_in[1];
    const int*   batch = (const int*)d_in[2];
    const float* W1    = (const float*)d_in[3];
    const float* b1    = (const float*)d_in[4];
    const float* W2    = (const float*)d_in[5];
    const float* b2    = (const float*)d_in[6];
    const float* W3    = (const float*)d_in[7];
    const float* b3    = (const float*)d_in[8];
    const float* Wlin  = (const float*)d_in[9];
    const float* blin  = (const float*)d_in[10];
    const int* src = ei;
    const int* dst = ei + NE;
    float* out = (float*)d_out;

    // workspace layout (all offsets keep 16B alignment)
    int*   bhist   = (int*)d_ws;                    // 256
    int*   bbase   = bhist + 256;                   // 256 (uses NBKT+1)
    int*   bcur    = bbase + 256;                   // 256
    int*   row_ptr = bcur + 256;                    // 50008
    int*   csr_src = row_ptr + 50008;               // 800000
    float* dinv    = (float*)(csr_src + NE);        // 50008
    float* bufA    = dinv + 50008;                  // 3.2M
    float* bufB    = bufA + (size_t)NN * NF;        // 3.2M (aliased as pairs in build)
    float* partial = bufB + (size_t)NN * NF;        // 131072
    int2*  pairs   = (int2*)bufB;                   // 6.4MB <= bufB, used only pre-layer

    // CSR build (bucket counting sort) + dinv + prescale
    zero_kernel<<<1, 256, 0, stream>>>(bhist, 256);
    bhist_kernel<<<(NE / 4 + 255) / 256, 256, 0, stream>>>(dst, bhist, NE);
    bscan_kernel<<<1, 256, 0, stream>>>(bhist, bbase, bcur);
    bscatter_kernel<<<(NE + CH - 1) / CH, 256, 0, stream>>>(src, dst, bcur, pairs, NE);
    bsort_kernel<<<NBKT, 256, 0, stream>>>(pairs, bbase, csr_src, row_ptr, dinv, x, bufA, NN);

    // 3 fused GCN layers (16 nodes per block, 4 per wave)
    int lgrid = (NN + 15) / 16;
    layer_kernel<<<lgrid, 256, 0, stream>>>(bufA, row_ptr, csr_src, dinv, W1, b1,
                                            bufB, NN, 1, 1);
    layer_kernel<<<lgrid, 256, 0, stream>>>(bufB, row_ptr, csr_src, dinv, W2, b2,
                                            bufA, NN, 1, 1);
    layer_kernel<<<lgrid, 256, 0, stream>>>(bufA, row_ptr, csr_src, dinv, W3, b3,
                                            bufB, NN, 0, 0);

    // two-stage pool + fused classifier
    pool1_kernel<<<NG * NSLICE, 256, 0, stream>>>(bufB, batch, partial, NN);
    pool2_kernel<<<NG, 128, 0, stream>>>(partial, batch, Wlin, blin, out, NN);
}

// Round 10
// 191.281 us; speedup vs baseline: 1.1488x; 1.0021x over previous
//
#include <hip/hip_runtime.h>

#define NN 50000
#define NE 800000
#define NF 64
#define NG 64
#define NC 16
#define NSLICE 16
#define NBKT 196   // buckets of 256 nodes: ceil(NN/256)
#define CH 4096    // edges per scatter block
#define SCAP 6144  // per-bucket LDS stage capacity (mean 4096, sigma~64)

// ---- CSR build: two-level bucket counting sort ---------------------------

__global__ void zero_kernel(int* __restrict__ p, int n) {
    for (int i = threadIdx.x; i < n; i += 256) p[i] = 0;
}

// P1a: per-bucket histogram (LDS-staged)
__global__ void bhist_kernel(const int* __restrict__ dst, int* __restrict__ bhist, int E) {
    __shared__ int lh[NBKT];
    for (int i = threadIdx.x; i < NBKT; i += 256) lh[i] = 0;
    __syncthreads();
    int e = (blockIdx.x * 256 + threadIdx.x) * 4;
    if (e + 3 < E) {
        int4 d = *(const int4*)&dst[e];
        atomicAdd(&lh[d.x >> 8], 1); atomicAdd(&lh[d.y >> 8], 1);
        atomicAdd(&lh[d.z >> 8], 1); atomicAdd(&lh[d.w >> 8], 1);
    } else {
        for (int k = e; k < E; ++k) atomicAdd(&lh[dst[k] >> 8], 1);
    }
    __syncthreads();
    for (int i = threadIdx.x; i < NBKT; i += 256) if (lh[i]) atomicAdd(&bhist[i], lh[i]);
}

// P1b: scan bucket hist -> bucket_base (+total), init bucket cursors
__global__ void bscan_kernel(const int* __restrict__ bhist, int* __restrict__ bbase,
                             int* __restrict__ bcur) {
    int tid = threadIdx.x, lane = tid & 63, wid = tid >> 6;
    int v = (tid < NBKT) ? bhist[tid] : 0;
    int s = v;
    #pragma unroll
    for (int d = 1; d < 64; d <<= 1) { int t = __shfl_up(s, d, 64); if (lane >= d) s += t; }
    __shared__ int ws[4];
    if (lane == 63) ws[wid] = s;
    __syncthreads();
    int woff = 0;
    for (int k = 0; k < wid; ++k) woff += ws[k];
    int excl = woff + s - v;
    if (tid < NBKT) { bbase[tid] = excl; bcur[tid] = excl; }
    if (tid == NBKT) bbase[NBKT] = excl;
}

// P1c: scatter edges into bucket regions of `pairs`, LDS-staged so global
// writes are contiguous bursts per bucket.
__global__ void __launch_bounds__(256) bscatter_kernel(
        const int* __restrict__ src, const int* __restrict__ dst,
        int* __restrict__ bcur, int2* __restrict__ pairs, int E) {
    __shared__ int lhist[NBKT];
    __shared__ int lbase[NBKT];
    __shared__ int gbase[NBKT];
    __shared__ int2 stage[CH];
    __shared__ short bktOf[CH];
    __shared__ int ws[4];
    int tid = threadIdx.x, lane = tid & 63, wid = tid >> 6;
    for (int i = tid; i < NBKT; i += 256) lhist[i] = 0;
    __syncthreads();
    int e0 = blockIdx.x * CH;
    int m = E - e0; if (m > CH) m = CH;
    int es[16], ed[16], er[16];
    #pragma unroll
    for (int k = 0; k < 16; ++k) {
        int i = tid + k * 256;
        if (i < m) {
            es[k] = src[e0 + i];
            ed[k] = dst[e0 + i];
            er[k] = atomicAdd(&lhist[ed[k] >> 8], 1);
        }
    }
    __syncthreads();
    {
        int v = (tid < NBKT) ? lhist[tid] : 0;
        int s = v;
        #pragma unroll
        for (int d = 1; d < 64; d <<= 1) { int t = __shfl_up(s, d, 64); if (lane >= d) s += t; }
        if (lane == 63) ws[wid] = s;
        __syncthreads();
        int woff = 0;
        for (int k = 0; k < wid; ++k) woff += ws[k];
        if (tid < NBKT) {
            lbase[tid] = woff + s - v;
            gbase[tid] = v ? atomicAdd(&bcur[tid], v) : 0;
        }
    }
    __syncthreads();
    #pragma unroll
    for (int k = 0; k < 16; ++k) {
        int i = tid + k * 256;
        if (i < m) {
            int b = ed[k] >> 8;
            int pos = lbase[b] + er[k];
            stage[pos] = make_int2(es[k], ed[k]);
            bktOf[pos] = (short)b;
        }
    }
    __syncthreads();
    for (int i = tid; i < m; i += 256) {
        int b = bktOf[i];
        pairs[gbase[b] + (i - lbase[b])] = stage[i];
    }
}

// P2: per-bucket counting sort by dst -> csr_src (coalesced, PRE-SHIFTED by
// <<4 = float4-row offset), row_ptr, dinv, fused prescale Xs = x*dinv.
__global__ void __launch_bounds__(256) bsort_kernel(
        const int2* __restrict__ pairs, const int* __restrict__ bbase,
        int* __restrict__ csr_src, int* __restrict__ row_ptr, float* __restrict__ dinv,
        const float* __restrict__ x, float* __restrict__ Xs, int n) {
    __shared__ int lh[256];
    __shared__ int lcur[256];
    __shared__ float sdv[256];
    __shared__ int ws[4];
    __shared__ int ssrc[SCAP];
    int tid = threadIdx.x, lane = tid & 63, wid = tid >> 6;
    int b = blockIdx.x;
    int n0 = b << 8;
    int nodes = n - n0; if (nodes > 256) nodes = 256;
    int g0 = bbase[b], cnt = bbase[b + 1] - g0;
    lh[tid] = 0;
    __syncthreads();
    for (int i = tid; i < cnt; i += 256) atomicAdd(&lh[pairs[g0 + i].y - n0], 1);
    __syncthreads();
    int v = lh[tid];
    int s = v;
    #pragma unroll
    for (int d = 1; d < 64; d <<= 1) { int t = __shfl_up(s, d, 64); if (lane >= d) s += t; }
    if (lane == 63) ws[wid] = s;
    __syncthreads();
    int woff = 0;
    for (int k = 0; k < wid; ++k) woff += ws[k];
    int excl = woff + s - v;
    lcur[tid] = excl;
    float dv = rsqrtf((float)v + 1.0f);
    sdv[tid] = dv;
    if (tid < nodes) {
        row_ptr[n0 + tid] = g0 + excl;
        dinv[n0 + tid] = dv;
    }
    if (b == NBKT - 1 && tid == 0) row_ptr[n] = bbase[NBKT];
    __syncthreads();
    if (cnt <= SCAP) {
        for (int i = tid; i < cnt; i += 256) {
            int2 p = pairs[g0 + i];
            int pos = atomicAdd(&lcur[p.y - n0], 1);
            ssrc[pos] = p.x << 4;
        }
        __syncthreads();
        for (int i = tid; i < cnt; i += 256) csr_src[g0 + i] = ssrc[i];
    } else {
        for (int i = tid; i < cnt; i += 256) {
            int2 p = pairs[g0 + i];
            int pos = atomicAdd(&lcur[p.y - n0], 1);
            csr_src[g0 + pos] = p.x << 4;
        }
    }
    const float4* x4 = (const float4*)x;
    float4* Xs4 = (float4*)Xs;
    int t0 = n0 << 4;
    int tcnt = nodes << 4;
    for (int t = tid; t < tcnt; t += 256) {
        float4 vv = x4[t0 + t];
        float d = sdv[t >> 4];
        vv.x *= d; vv.y *= d; vv.z *= d; vv.w *= d;
        Xs4[t0 + t] = vv;
    }
}

// ---- fused GCN layer: pipelined index prefetch, 4 nodes/wave --------------
// Per node: wave gathers neighbor rows (4 grp x 16 lanes x float4, idx tile
// prefetched during previous node's matvec), xor-reduces, readlane matvec
// against xor-swizzled W^T in LDS (all LDS access conflict-free).
// NN % 16 == 0 -> no bounds checks in the node loop.
__global__ void __launch_bounds__(256) layer_kernel(
        const float* __restrict__ Xs, const int* __restrict__ row_ptr,
        const int* __restrict__ csr_src, const float* __restrict__ dinv,
        const float* __restrict__ W, const float* __restrict__ bias,
        float* __restrict__ out, int n, int do_relu, int scale_out) {
    __shared__ __align__(16) float sWt[64 * 64];  // row j: 16 xor-swizzled chunks
    {
        int j = threadIdx.x & 63;
        int c0 = (threadIdx.x >> 6) * 4;
        #pragma unroll
        for (int it = 0; it < 4; ++it) {
            int c = c0 + it;
            float4 w;
            w.x = W[(4 * c + 0) * 64 + j];
            w.y = W[(4 * c + 1) * 64 + j];
            w.z = W[(4 * c + 2) * 64 + j];
            w.w = W[(4 * c + 3) * 64 + j];
            *(float4*)&sWt[j * 64 + ((c ^ (j & 15)) * 4)] = w;
        }
    }
    __syncthreads();

    int wv = threadIdx.x >> 6, lane = threadIdx.x & 63;
    int grp = lane >> 4, sub = lane & 15;
    const float4* X4 = (const float4*)Xs;
    int base = blockIdx.x * 16 + wv * 4;
    float bj = bias[lane];

    // hoisted row pointers (wave-uniform -> scalar loads, one round)
    int rp[5];
    #pragma unroll
    for (int k = 0; k < 5; ++k) rp[k] = row_ptr[base + k];

    // prefetch node 0's index tile
    int m0 = rp[1] - rp[0]; if (m0 > 64) m0 = 64;
    int clamp0 = (m0 > 0) ? m0 - 1 : 0;
    int idxN = csr_src[rp[0] + ((lane < m0) ? lane : clamp0)];

    #pragma unroll
    for (int nd = 0; nd < 4; ++nd) {
        int node = base + nd;
        int s0 = rp[nd], s1 = rp[nd + 1];
        int m = s1 - s0; if (m > 64) m = 64;
        int idx = idxN;
        // prefetch next node's first index tile (hides under gather+matvec)
        if (nd < 3) {
            int mn = rp[nd + 2] - rp[nd + 1]; if (mn > 64) mn = 64;
            int cl = (mn > 0) ? mn - 1 : 0;
            idxN = csr_src[rp[nd + 1] + ((lane < mn) ? lane : cl)];
        }

        float4 acc = make_float4(0.f, 0.f, 0.f, 0.f);
        // first (and almost always only) 64-edge tile
        for (int e0 = grp; e0 < m; e0 += 16) {
            int e1 = e0 + 4, e2 = e0 + 8, e3 = e0 + 12;
            int i0 = __shfl(idx, e0, 64);
            int i1 = __shfl(idx, (e1 < m) ? e1 : e0, 64);
            int i2 = __shfl(idx, (e2 < m) ? e2 : e0, 64);
            int i3 = __shfl(idx, (e3 < m) ? e3 : e0, 64);
            float w1 = (e1 < m) ? 1.f : 0.f;
            float w2 = (e2 < m) ? 1.f : 0.f;
            float w3 = (e3 < m) ? 1.f : 0.f;
            float4 v0 = X4[(unsigned)(i0 + sub)];
            float4 v1 = X4[(unsigned)(i1 + sub)];
            float4 v2 = X4[(unsigned)(i2 + sub)];
            float4 v3 = X4[(unsigned)(i3 + sub)];
            acc.x += v0.x; acc.y += v0.y; acc.z += v0.z; acc.w += v0.w;
            acc.x = fmaf(w1, v1.x, acc.x); acc.y = fmaf(w1, v1.y, acc.y);
            acc.z = fmaf(w1, v1.z, acc.z); acc.w = fmaf(w1, v1.w, acc.w);
            acc.x = fmaf(w2, v2.x, acc.x); acc.y = fmaf(w2, v2.y, acc.y);
            acc.z = fmaf(w2, v2.z, acc.z); acc.w = fmaf(w2, v2.w, acc.w);
            acc.x = fmaf(w3, v3.x, acc.x); acc.y = fmaf(w3, v3.y, acc.y);
            acc.z = fmaf(w3, v3.z, acc.z); acc.w = fmaf(w3, v3.w, acc.w);
        }
        // rare extra tiles (degree > 64)
        for (int tb = s0 + 64; tb < s1; tb += 64) {
            int mm = s1 - tb; if (mm > 64) mm = 64;
            int idy = csr_src[tb + ((lane < mm) ? lane : mm - 1)];
            for (int e0 = grp; e0 < mm; e0 += 16) {
                int e1 = e0 + 4, e2 = e0 + 8, e3 = e0 + 12;
                int i0 = __shfl(idy, e0, 64);
                int i1 = __shfl(idy, (e1 < mm) ? e1 : e0, 64);
                int i2 = __shfl(idy, (e2 < mm) ? e2 : e0, 64);
                int i3 = __shfl(idy, (e3 < mm) ? e3 : e0, 64);
                float w1 = (e1 < mm) ? 1.f : 0.f;
                float w2 = (e2 < mm) ? 1.f : 0.f;
                float w3 = (e3 < mm) ? 1.f : 0.f;
                float4 v0 = X4[(unsigned)(i0 + sub)];
                float4 v1 = X4[(unsigned)(i1 + sub)];
                float4 v2 = X4[(unsigned)(i2 + sub)];
                float4 v3 = X4[(unsigned)(i3 + sub)];
                acc.x += v0.x; acc.y += v0.y; acc.z += v0.z; acc.w += v0.w;
                acc.x = fmaf(w1, v1.x, acc.x); acc.y = fmaf(w1, v1.y, acc.y);
                acc.z = fmaf(w1, v1.z, acc.z); acc.w = fmaf(w1, v1.w, acc.w);
                acc.x = fmaf(w2, v2.x, acc.x); acc.y = fmaf(w2, v2.y, acc.y);
                acc.z = fmaf(w2, v2.z, acc.z); acc.w = fmaf(w2, v2.w, acc.w);
                acc.x = fmaf(w3, v3.x, acc.x); acc.y = fmaf(w3, v3.y, acc.y);
                acc.z = fmaf(w3, v3.z, acc.z); acc.w = fmaf(w3, v3.w, acc.w);
            }
        }
        // self-loop (already dinv-scaled)
        if (grp == 0) {
            float4 sv = X4[(unsigned)(node * 16 + sub)];
            acc.x += sv.x; acc.y += sv.y; acc.z += sv.z; acc.w += sv.w;
        }
        // reduce the 4 edge-groups; lane ends with agg[4*sub .. 4*sub+3]
        acc.x += __shfl_xor(acc.x, 16, 64); acc.y += __shfl_xor(acc.y, 16, 64);
        acc.z += __shfl_xor(acc.z, 16, 64); acc.w += __shfl_xor(acc.w, 16, 64);
        acc.x += __shfl_xor(acc.x, 32, 64); acc.y += __shfl_xor(acc.y, 32, 64);
        acc.z += __shfl_xor(acc.z, 32, 64); acc.w += __shfl_xor(acc.w, 32, 64);

        // matvec: out_j = sum_c sum_r agg[4c+r] * W[4c+r][j]
        float o = 0.f;
        #pragma unroll
        for (int c = 0; c < 16; ++c) {
            float4 wvv = *(const float4*)&sWt[lane * 64 + ((c ^ (lane & 15)) * 4)];
            float a0 = __int_as_float(__builtin_amdgcn_readlane(__float_as_int(acc.x), c));
            float a1 = __int_as_float(__builtin_amdgcn_readlane(__float_as_int(acc.y), c));
            float a2 = __int_as_float(__builtin_amdgcn_readlane(__float_as_int(acc.z), c));
            float a3 = __int_as_float(__builtin_amdgcn_readlane(__float_as_int(acc.w), c));
            o = fmaf(a0, wvv.x, o); o = fmaf(a1, wvv.y, o);
            o = fmaf(a2, wvv.z, o); o = fmaf(a3, wvv.w, o);
        }
        float di = dinv[node];
        float vv = o * di + bj;
        if (do_relu) vv = fmaxf(vv, 0.f);
        if (scale_out) vv *= di;
        out[(unsigned)(node * 64 + lane)] = vv;
    }
}

// ---- pooling / classifier ------------------------------------------------

__global__ void pool1_kernel(const float* __restrict__ H, const int* __restrict__ batch,
                             float* __restrict__ partial, int n) {
    int g = blockIdx.x >> 4, sl = blockIdx.x & (NSLICE - 1);
    int lo = 0, hi = n;
    while (lo < hi) { int m = (lo + hi) >> 1; if (batch[m] < g) lo = m + 1; else hi = m; }
    int start = lo;
    lo = start; hi = n;
    while (lo < hi) { int m = (lo + hi) >> 1; if (batch[m] < g + 1) lo = m + 1; else hi = m; }
    int end = lo;
    int len = end - start;
    int ss = start + (int)((long long)len * sl / NSLICE);
    int se = start + (int)((long long)len * (sl + 1) / NSLICE);

    int f = threadIdx.x & 63, c = threadIdx.x >> 6;
    float s = 0.f, m = -INFINITY;
    for (int i = ss + c; i < se; i += 4) {
        float v = H[i * NF + f];
        s += v; m = fmaxf(m, v);
    }
    __shared__ float ssh[4][64], smh[4][64];
    ssh[c][f] = s; smh[c][f] = m;
    __syncthreads();
    if (c == 0) {
        float sum = ssh[0][f] + ssh[1][f] + ssh[2][f] + ssh[3][f];
        float mx = fmaxf(fmaxf(smh[0][f], smh[1][f]), fmaxf(smh[2][f], smh[3][f]));
        partial[(size_t)blockIdx.x * 128 + f] = sum;
        partial[(size_t)blockIdx.x * 128 + 64 + f] = mx;
    }
}

__global__ void pool2_kernel(const float* __restrict__ partial, const int* __restrict__ batch,
                             const float* __restrict__ Wlin, const float* __restrict__ blin,
                             float* __restrict__ out, int n) {
    int g = blockIdx.x;
    int t = threadIdx.x;  // 128
    __shared__ float pooled[128];
    if (t < 64) {
        float sum = 0.f;
        for (int sl = 0; sl < NSLICE; ++sl) sum += partial[((size_t)g * NSLICE + sl) * 128 + t];
        int lo = 0, hi = n;
        while (lo < hi) { int m = (lo + hi) >> 1; if (batch[m] < g) lo = m + 1; else hi = m; }
        int start = lo;
        lo = start; hi = n;
        while (lo < hi) { int m = (lo + hi) >> 1; if (batch[m] < g + 1) lo = m + 1; else hi = m; }
        int cnt = lo - start;
        pooled[t] = sum / fmaxf((float)cnt, 1.0f);
    } else {
        int f = t - 64;
        float mx = -INFINITY;
        for (int sl = 0; sl < NSLICE; ++sl)
            mx = fmaxf(mx, partial[((size_t)g * NSLICE + sl) * 128 + 64 + f]);
        pooled[t] = mx;
    }
    __syncthreads();
    if (t < NC) {
        float acc = blin[t];
        #pragma unroll 8
        for (int k = 0; k < 128; ++k) acc = fmaf(pooled[k], Wlin[k * NC + t], acc);
        out[g * NC + t] = acc;
    }
}

// ---- launch ---------------------------------------------------------------

extern "C" void kernel_launch(void* const* d_in, const int* in_sizes, int n_in,
                              void* d_out, int out_size, void* d_ws, size_t ws_size,
                              hipStream_t stream) {
    const float* x     = (const float*)d_in[0];
    const int*   ei    = (const int*)d_in[1];
    const int*   batch = (const int*)d_in[2];
    const float* W1    = (const float*)d_in[3];
    const float* b1    = (const float*)d_in[4];
    const float* W2    = (const float*)d_in[5];
    const float* b2    = (const float*)d_in[6];
    const float* W3    = (const float*)d_in[7];
    const float* b3    = (const float*)d_in[8];
    const float* Wlin  = (const float*)d_in[9];
    const float* blin  = (const float*)d_in[10];
    const int* src = ei;
    const int* dst = ei + NE;
    float* out = (float*)d_out;

    // workspace layout (all offsets keep 16B alignment)
    int*   bhist   = (int*)d_ws;                    // 256
    int*   bbase   = bhist + 256;                   // 256 (uses NBKT+1)
    int*   bcur    = bbase + 256;                   // 256
    int*   row_ptr = bcur + 256;                    // 50008
    int*   csr_src = row_ptr + 50008;               // 800000
    float* dinv    = (float*)(csr_src + NE);        // 50008
    float* bufA    = dinv + 50008;                  // 3.2M
    float* bufB    = bufA + (size_t)NN * NF;        // 3.2M (aliased as pairs in build)
    float* partial = bufB + (size_t)NN * NF;        // 131072
    int2*  pairs   = (int2*)bufB;                   // 6.4MB <= bufB, used only pre-layer

    // CSR build (bucket counting sort) + dinv + prescale
    zero_kernel<<<1, 256, 0, stream>>>(bhist, 256);
    bhist_kernel<<<(NE / 4 + 255) / 256, 256, 0, stream>>>(dst, bhist, NE);
    bscan_kernel<<<1, 256, 0, stream>>>(bhist, bbase, bcur);
    bscatter_kernel<<<(NE + CH - 1) / CH, 256, 0, stream>>>(src, dst, bcur, pairs, NE);
    bsort_kernel<<<NBKT, 256, 0, stream>>>(pairs, bbase, csr_src, row_ptr, dinv, x, bufA, NN);

    // 3 fused GCN layers (16 nodes per block, 4 per wave)
    int lgrid = (NN + 15) / 16;
    layer_kernel<<<lgrid, 256, 0, stream>>>(bufA, row_ptr, csr_src, dinv, W1, b1,
                                            bufB, NN, 1, 1);
    layer_kernel<<<lgrid, 256, 0, stream>>>(bufB, row_ptr, csr_src, dinv, W2, b2,
                                            bufA, NN, 1, 1);
    layer_kernel<<<lgrid, 256, 0, stream>>>(bufA, row_ptr, csr_src, dinv, W3, b3,
                                            bufB, NN, 0, 0);

    // two-stage pool + fused classifier
    pool1_kernel<<<NG * NSLICE, 256, 0, stream>>>(bufB, batch, partial, NN);
    pool2_kernel<<<NG, 128, 0, stream>>>(partial, batch, Wlin, blin, out, NN);
}